// Round 1
// baseline (217.517 us; speedup 1.0000x reference)
//
#include <hip/hip_runtime.h>
#include <cstdint>

typedef float f32x4 __attribute__((ext_vector_type(4)));
typedef __bf16 bf16x8 __attribute__((ext_vector_type(8)));

__device__ __forceinline__ unsigned short f2b(float f) {
  unsigned int u = __float_as_uint(f);
  u = (u + 0x7fffu + ((u >> 16) & 1u)) >> 16;
  return (unsigned short)u;
}

__device__ __forceinline__ void unpack8(uint4 u, float* f) {
  f[0] = __uint_as_float((u.x & 0xffffu) << 16);
  f[1] = __uint_as_float(u.x & 0xffff0000u);
  f[2] = __uint_as_float((u.y & 0xffffu) << 16);
  f[3] = __uint_as_float(u.y & 0xffff0000u);
  f[4] = __uint_as_float((u.z & 0xffffu) << 16);
  f[5] = __uint_as_float(u.z & 0xffff0000u);
  f[6] = __uint_as_float((u.w & 0xffffu) << 16);
  f[7] = __uint_as_float(u.w & 0xffff0000u);
}

__device__ __forceinline__ void async_copy16(const void* g, void* l) {
  __builtin_amdgcn_global_load_lds(
      (const __attribute__((address_space(1))) void*)g,
      (__attribute__((address_space(3))) void*)l, 16, 0, 0);
}

// ---- convert x (f32, [nrows][fin]) -> bf16 padded [mpad][fin], pad rows = 0
__global__ __launch_bounds__(256) void convx_kernel(
    const float* __restrict__ x, unsigned short* __restrict__ xb,
    int nrows, int mpad, int fin) {
  int i8 = blockIdx.x * 256 + threadIdx.x;
  int total = mpad * fin / 8;
  if (i8 >= total) return;
  int row = (i8 * 8) / fin;
  unsigned short o[8];
  if (row < nrows) {
    const float4* p = (const float4*)(x + (size_t)i8 * 8);
    float4 a = p[0], b = p[1];
    o[0] = f2b(a.x); o[1] = f2b(a.y); o[2] = f2b(a.z); o[3] = f2b(a.w);
    o[4] = f2b(b.x); o[5] = f2b(b.y); o[6] = f2b(b.z); o[7] = f2b(b.w);
  } else {
#pragma unroll
    for (int j = 0; j < 8; ++j) o[j] = 0;
  }
  uint4 w;
  w.x = (unsigned int)o[0] | ((unsigned int)o[1] << 16);
  w.y = (unsigned int)o[2] | ((unsigned int)o[3] << 16);
  w.z = (unsigned int)o[4] | ((unsigned int)o[5] << 16);
  w.w = (unsigned int)o[6] | ((unsigned int)o[7] << 16);
  *(uint4*)(xb + (size_t)i8 * 8) = w;
}

// ---- transpose W (f32 [K][NT]) -> Wt (bf16 [NT][K])
__global__ __launch_bounds__(1024) void convw_kernel(
    const float* __restrict__ W, unsigned short* __restrict__ Wt, int K, int NT) {
  __shared__ float tile[32][33];
  int tx = threadIdx.x, ty = threadIdx.y;
  int n0 = blockIdx.x * 32, k0 = blockIdx.y * 32;
  tile[ty][tx] = W[(size_t)(k0 + ty) * NT + n0 + tx];
  __syncthreads();
  Wt[(size_t)(n0 + ty) * K + k0 + tx] = f2b(tile[tx][ty]);
}

// ---- GEMM: C[mpad][NT] = A[mpad][K] * B[K][NT], B given as Bt[NT][K], all bf16
__global__ __launch_bounds__(256) void gemm_kernel(
    const unsigned short* __restrict__ A, const unsigned short* __restrict__ Bt,
    unsigned short* __restrict__ C, int K, int NT) {
  __shared__ __align__(16) unsigned short As[128 * 32];
  __shared__ __align__(16) unsigned short Bs[128 * 32];
  int tid = threadIdx.x;
  int wave = tid >> 6, lane = tid & 63;
  int m0 = blockIdx.x * 128, n0 = blockIdx.y * 128;
  int wr = wave >> 1, wc = wave & 1;
  f32x4 acc[4][4] = {};

  int c0 = wave, c1 = wave + 4;
  int rr0 = c0 * 16 + (lane >> 2), rr1 = c1 * 16 + (lane >> 2);
  int kc = (lane & 3) * 8;
  const unsigned short* gA0 = A + (size_t)(m0 + rr0) * K + kc;
  const unsigned short* gA1 = A + (size_t)(m0 + rr1) * K + kc;
  const unsigned short* gB0 = Bt + (size_t)(n0 + rr0) * K + kc;
  const unsigned short* gB1 = Bt + (size_t)(n0 + rr1) * K + kc;

  int ra = (wr * 64 + (lane & 15)) * 32 + (lane >> 4) * 8;
  int rb = (wc * 64 + (lane & 15)) * 32 + (lane >> 4) * 8;

  for (int kt = 0; kt < K; kt += 32) {
    async_copy16(gA0 + kt, &As[c0 * 512]);
    async_copy16(gA1 + kt, &As[c1 * 512]);
    async_copy16(gB0 + kt, &Bs[c0 * 512]);
    async_copy16(gB1 + kt, &Bs[c1 * 512]);
    __syncthreads();
    bf16x8 af[4], bfr[4];
#pragma unroll
    for (int i = 0; i < 4; ++i) af[i] = *(const bf16x8*)&As[ra + i * 16 * 32];
#pragma unroll
    for (int j = 0; j < 4; ++j) bfr[j] = *(const bf16x8*)&Bs[rb + j * 16 * 32];
#pragma unroll
    for (int i = 0; i < 4; ++i)
#pragma unroll
      for (int j = 0; j < 4; ++j)
        acc[i][j] = __builtin_amdgcn_mfma_f32_16x16x32_bf16(af[i], bfr[j], acc[i][j], 0, 0, 0);
    __syncthreads();
  }

  int col0 = n0 + wc * 64 + (lane & 15);
  int row0 = m0 + wr * 64 + (lane >> 4) * 4;
#pragma unroll
  for (int i = 0; i < 4; ++i)
#pragma unroll
    for (int j = 0; j < 4; ++j) {
      int r = row0 + i * 16;
      int cc = col0 + j * 16;
#pragma unroll
      for (int q = 0; q < 4; ++q)
        C[(size_t)(r + q) * NT + cc] = f2b(acc[i][j][q]);
    }
}

// ---- CSR build
__global__ __launch_bounds__(256) void count_kernel(const int* __restrict__ src,
                                                    int* __restrict__ deg, int E) {
  int e = blockIdx.x * 256 + threadIdx.x;
  if (e < E) atomicAdd(&deg[src[e]], 1);
}

__global__ __launch_bounds__(1024) void scan_kernel(
    const int* __restrict__ deg, int* __restrict__ offs, int* __restrict__ cursor, int n) {
  __shared__ int sums[1024];
  int t = threadIdx.x;
  int chunk = (n + 1023) / 1024;
  int s0 = t * chunk, s1 = min(s0 + chunk, n);
  int s = 0;
  for (int i = s0; i < s1; ++i) s += deg[i];
  sums[t] = s;
  __syncthreads();
  for (int off = 1; off < 1024; off <<= 1) {
    int v = (t >= off) ? sums[t - off] : 0;
    __syncthreads();
    sums[t] += v;
    __syncthreads();
  }
  int run = (t == 0) ? 0 : sums[t - 1];
  for (int i = s0; i < s1; ++i) {
    offs[i] = run;
    cursor[i] = run;
    run += deg[i];
  }
  if (t == 1023) offs[n] = run;
}

__global__ __launch_bounds__(256) void scatter_kernel(
    const int* __restrict__ src, const int* __restrict__ dst,
    int* __restrict__ cursor, int* __restrict__ edst, int E) {
  int e = blockIdx.x * 256 + threadIdx.x;
  if (e < E) {
    int pos = atomicAdd(&cursor[src[e]], 1);
    edst[pos] = dst[e];
  }
}

// ---- fused flash-style segment attention: one wave per src node
__global__ __launch_bounds__(256) void attn_kernel(
    const unsigned short* __restrict__ qkv, const int* __restrict__ offs,
    const int* __restrict__ edst, float* __restrict__ out, int n) {
  int wave = threadIdx.x >> 6, lane = threadIdx.x & 63;
  int node = blockIdx.x * 4 + wave;
  if (node >= n) return;

  const unsigned short* qp = qkv + (size_t)node * 1536 + lane * 8;
  float q[8];
  unpack8(*(const uint4*)qp, q);

  float acc[8] = {0.f, 0.f, 0.f, 0.f, 0.f, 0.f, 0.f, 0.f};
  float m = -__builtin_inff(), l = 0.f;
  int beg = offs[node], end = offs[node + 1];
  for (int i = beg; i < end; ++i) {
    int d = edst[i];
    const unsigned short* kp = qkv + (size_t)d * 1536 + 512 + lane * 8;
    uint4 kv = *(const uint4*)kp;
    uint4 vv = *(const uint4*)(kp + 512);
    float kf[8], vf[8];
    unpack8(kv, kf);
    unpack8(vv, vf);
    float part = 0.f;
#pragma unroll
    for (int j = 0; j < 8; ++j) part = fmaf(q[j], kf[j], part);
    part += __shfl_xor(part, 1);
    part += __shfl_xor(part, 2);
    part += __shfl_xor(part, 4);
    float s = part * 0.125f;  // 1/sqrt(64)
    float mn = fmaxf(m, s);
    float sc = __expf(m - mn);
    float p = __expf(s - mn);
    l = l * sc + p;
#pragma unroll
    for (int j = 0; j < 8; ++j) acc[j] = acc[j] * sc + p * vf[j];
    m = mn;
  }
  float inv = (l > 0.f) ? 1.f / l : 0.f;
  float4 o0, o1;
  o0.x = acc[0] * inv; o0.y = acc[1] * inv; o0.z = acc[2] * inv; o0.w = acc[3] * inv;
  o1.x = acc[4] * inv; o1.y = acc[5] * inv; o1.z = acc[6] * inv; o1.w = acc[7] * inv;
  float4* op = (float4*)(out + (size_t)node * 512 + lane * 8);
  op[0] = o0;
  op[1] = o1;
}

extern "C" void kernel_launch(void* const* d_in, const int* in_sizes, int n_in,
                              void* d_out, int out_size, void* d_ws, size_t ws_size,
                              hipStream_t stream) {
  const float* x = (const float*)d_in[0];
  const int* ei = (const int*)d_in[2];
  const float* W = (const float*)d_in[3];
  float* out = (float*)d_out;

  const int N = in_sizes[1];        // 20000 nodes
  const int E = in_sizes[2] / 2;    // 250000 edges
  const int Fin = in_sizes[0] / N;  // 512
  const int FT = in_sizes[3] / Fin; // 1536 = 2*Fqk + Fv
  const int MPAD = ((N + 127) / 128) * 128;

  const int* src = ei;
  const int* dst = ei + E;

  char* ws = (char*)d_ws;
  size_t off = 0;
  auto alloc = [&](size_t bytes) {
    void* p = ws + off;
    off = (off + bytes + 255) & ~(size_t)255;
    return p;
  };
  unsigned short* xb  = (unsigned short*)alloc((size_t)MPAD * Fin * 2);
  unsigned short* Wt  = (unsigned short*)alloc((size_t)FT * Fin * 2);
  unsigned short* qkv = (unsigned short*)alloc((size_t)MPAD * FT * 2);
  int* deg    = (int*)alloc((size_t)N * 4);
  int* offs   = (int*)alloc((size_t)(N + 1) * 4);
  int* cursor = (int*)alloc((size_t)N * 4);
  int* edst   = (int*)alloc((size_t)E * 4);

  hipMemsetAsync(deg, 0, (size_t)N * 4, stream);

  int total8 = MPAD * Fin / 8;
  convx_kernel<<<(total8 + 255) / 256, 256, 0, stream>>>(x, xb, N, MPAD, Fin);
  convw_kernel<<<dim3(FT / 32, Fin / 32), dim3(32, 32), 0, stream>>>(W, Wt, Fin, FT);
  gemm_kernel<<<dim3(MPAD / 128, FT / 128), 256, 0, stream>>>(xb, Wt, qkv, Fin, FT);
  count_kernel<<<(E + 255) / 256, 256, 0, stream>>>(src, deg, E);
  scan_kernel<<<1, 1024, 0, stream>>>(deg, offs, cursor, N);
  scatter_kernel<<<(E + 255) / 256, 256, 0, stream>>>(src, dst, cursor, edst, E);
  attn_kernel<<<(N + 3) / 4, 256, 0, stream>>>(qkv, offs, edst, out, N);
}